// Round 3
// baseline (108.142 us; speedup 1.0000x reference)
//
#include <hip/hip_runtime.h>
#include <stdint.h>

// Problem constants (fixed by setup_inputs): B=8, C=4, N=16, H=W=256.
constexpr int HW      = 256 * 256;          // 65536 pixels per (b)
constexpr int C       = 4;
constexpr int N       = 16;
constexpr int BATCH   = 8;
constexpr int GROUPS  = BATCH * (HW / 4);   // one thread per 4 pixels = 131072
constexpr int BLOCK   = 256;
constexpr int GRID    = GROUPS / BLOCK;     // 512 blocks
constexpr float INV_COUNT = 1.0f / 33554432.0f;  // 1 / (B*N*C*H*W)

// Per-pixel identity (masks are 0/1 so m^2 == m):
//   sum_{n,c} (pd_c*pm_n - gt_c*gm_n)^2 = a*P + b*G - 2*ab*X
// with P=sum_c pd_c^2, G=sum_c gt_c^2, X=sum_c pd_c*gt_c,
//      a=sum_n pm_n, b=sum_n gm_n, ab=sum_n pm_n*gm_n.
// NOTE (round-2 lesson): harness delivers jax bool as int32 (one int per
// element). Computed-value-of-exactly-0.25 confirmed the byte-bool reading
// was wrong; masks are [b][n][h][w] int32 with values {0,1}.
__global__ __launch_bounds__(BLOCK) void mse_partial_kernel(
    const float* __restrict__ pd, const float* __restrict__ gt,
    const int* __restrict__ pdm, const int* __restrict__ gtm,
    float* __restrict__ partial)
{
    const int g   = blockIdx.x * BLOCK + threadIdx.x;  // [0, 131072)
    const int b   = g >> 14;                           // / (HW/4)
    const int pix = (g & 16383) << 2;                  // first of 4 pixels

    const float4* pd4 = reinterpret_cast<const float4*>(pd + (size_t)b * C * HW + pix);
    const float4* gt4 = reinterpret_cast<const float4*>(gt + (size_t)b * C * HW + pix);

    float P[4]  = {0.f, 0.f, 0.f, 0.f};
    float Gs[4] = {0.f, 0.f, 0.f, 0.f};
    float X[4]  = {0.f, 0.f, 0.f, 0.f};
    #pragma unroll
    for (int c = 0; c < C; ++c) {
        float4 p = pd4[c * (HW / 4)];
        float4 q = gt4[c * (HW / 4)];
        P[0] = fmaf(p.x, p.x, P[0]); Gs[0] = fmaf(q.x, q.x, Gs[0]); X[0] = fmaf(p.x, q.x, X[0]);
        P[1] = fmaf(p.y, p.y, P[1]); Gs[1] = fmaf(q.y, q.y, Gs[1]); X[1] = fmaf(p.y, q.y, X[1]);
        P[2] = fmaf(p.z, p.z, P[2]); Gs[2] = fmaf(q.z, q.z, Gs[2]); X[2] = fmaf(p.z, q.z, X[2]);
        P[3] = fmaf(p.w, p.w, P[3]); Gs[3] = fmaf(q.w, q.w, Gs[3]); X[3] = fmaf(p.w, q.w, X[3]);
    }

    // Mask counts: int4 load covers this thread's 4 pixels for one n.
    const int4* pmu = reinterpret_cast<const int4*>(pdm + (size_t)b * N * HW + pix);
    const int4* gmu = reinterpret_cast<const int4*>(gtm + (size_t)b * N * HW + pix);
    int ca[4]  = {0, 0, 0, 0};
    int cb[4]  = {0, 0, 0, 0};
    int cab[4] = {0, 0, 0, 0};
    #pragma unroll
    for (int n = 0; n < N; ++n) {
        int4 am = pmu[n * (HW / 4)];
        int4 bm = gmu[n * (HW / 4)];
        ca[0] += am.x; cb[0] += bm.x; cab[0] += am.x & bm.x;
        ca[1] += am.y; cb[1] += bm.y; cab[1] += am.y & bm.y;
        ca[2] += am.z; cb[2] += bm.z; cab[2] += am.z & bm.z;
        ca[3] += am.w; cb[3] += bm.w; cab[3] += am.w & bm.w;
    }

    float acc = 0.0f;
    #pragma unroll
    for (int j = 0; j < 4; ++j) {
        acc += (float)ca[j] * P[j] + (float)cb[j] * Gs[j]
             - 2.0f * (float)cab[j] * X[j];
    }

    // Wave(64) shuffle reduce, then cross-wave via LDS.
    #pragma unroll
    for (int off = 32; off > 0; off >>= 1)
        acc += __shfl_down(acc, off, 64);

    __shared__ float sacc[BLOCK / 64];
    const int lane = threadIdx.x & 63;
    const int wave = threadIdx.x >> 6;
    if (lane == 0) sacc[wave] = acc;
    __syncthreads();
    if (threadIdx.x == 0)
        partial[blockIdx.x] = sacc[0] + sacc[1] + sacc[2] + sacc[3];
}

__global__ __launch_bounds__(BLOCK) void mse_final_kernel(
    const float* __restrict__ partial, float* __restrict__ out)
{
    // GRID=512 partials, 256 threads: 2 each.
    float acc = partial[threadIdx.x] + partial[threadIdx.x + BLOCK];
    #pragma unroll
    for (int off = 32; off > 0; off >>= 1)
        acc += __shfl_down(acc, off, 64);

    __shared__ float sacc[BLOCK / 64];
    const int lane = threadIdx.x & 63;
    const int wave = threadIdx.x >> 6;
    if (lane == 0) sacc[wave] = acc;
    __syncthreads();
    if (threadIdx.x == 0)
        out[0] = (sacc[0] + sacc[1] + sacc[2] + sacc[3]) * INV_COUNT;
}

extern "C" void kernel_launch(void* const* d_in, const int* in_sizes, int n_in,
                              void* d_out, int out_size, void* d_ws, size_t ws_size,
                              hipStream_t stream) {
    const float* pd  = (const float*)d_in[0];
    const float* gt  = (const float*)d_in[1];
    const int*   pdm = (const int*)d_in[2];   // jax bool -> int32 per harness
    const int*   gtm = (const int*)d_in[3];
    float* out     = (float*)d_out;
    float* partial = (float*)d_ws;            // 512 floats, all written each call

    mse_partial_kernel<<<GRID, BLOCK, 0, stream>>>(pd, gt, pdm, gtm, partial);
    mse_final_kernel<<<1, BLOCK, 0, stream>>>(partial, out);
}